// Round 1
// baseline (2324.882 us; speedup 1.0000x reference)
//
#include <hip/hip_runtime.h>
#include <math.h>

// Problem constants: B=8, S=1024, D=1024, H=16, HD=64
// qkv row layout per token: [h0: q(64) k(64) v(64), h1: ...] (192 per head)

#define BM 128
#define BN 128
#define BKK 16

// C[M,N] = A[M,K] @ B[N,K]^T + bias[N]   (all row-major fp32)
__global__ __launch_bounds__(256) void gemm_nt_bias(
    const float* __restrict__ A, const float* __restrict__ B,
    const float* __restrict__ bias, float* __restrict__ C,
    int M, int N, int K)
{
    __shared__ float As[BKK][BM + 4];
    __shared__ float Bs[BKK][BN + 4];

    const int tid = threadIdx.x;
    const int tx = tid & 15;        // 0..15  -> N direction
    const int ty = tid >> 4;        // 0..15  -> M direction
    const int bn = blockIdx.x * BN;
    const int bm = blockIdx.y * BM;

    float acc[8][8];
#pragma unroll
    for (int i = 0; i < 8; ++i)
#pragma unroll
        for (int j = 0; j < 8; ++j) acc[i][j] = 0.f;

    const int a_r = tid >> 2;         // 0..63
    const int a_k = (tid & 3) * 4;    // 0,4,8,12

    for (int k0 = 0; k0 < K; k0 += BKK) {
        float4 av0 = *(const float4*)&A[(size_t)(bm + a_r) * K + k0 + a_k];
        float4 av1 = *(const float4*)&A[(size_t)(bm + a_r + 64) * K + k0 + a_k];
        float4 bv0 = *(const float4*)&B[(size_t)(bn + a_r) * K + k0 + a_k];
        float4 bv1 = *(const float4*)&B[(size_t)(bn + a_r + 64) * K + k0 + a_k];

        __syncthreads();   // previous tile's compute done before overwrite

        As[a_k + 0][a_r] = av0.x; As[a_k + 1][a_r] = av0.y;
        As[a_k + 2][a_r] = av0.z; As[a_k + 3][a_r] = av0.w;
        As[a_k + 0][a_r + 64] = av1.x; As[a_k + 1][a_r + 64] = av1.y;
        As[a_k + 2][a_r + 64] = av1.z; As[a_k + 3][a_r + 64] = av1.w;
        Bs[a_k + 0][a_r] = bv0.x; Bs[a_k + 1][a_r] = bv0.y;
        Bs[a_k + 2][a_r] = bv0.z; Bs[a_k + 3][a_r] = bv0.w;
        Bs[a_k + 0][a_r + 64] = bv1.x; Bs[a_k + 1][a_r + 64] = bv1.y;
        Bs[a_k + 2][a_r + 64] = bv1.z; Bs[a_k + 3][a_r + 64] = bv1.w;

        __syncthreads();

#pragma unroll
        for (int k = 0; k < BKK; ++k) {
            float4 a0 = *(const float4*)&As[k][ty * 4];
            float4 a1 = *(const float4*)&As[k][64 + ty * 4];
            float4 b0 = *(const float4*)&Bs[k][tx * 4];
            float4 b1 = *(const float4*)&Bs[k][64 + tx * 4];
            float ar[8] = {a0.x, a0.y, a0.z, a0.w, a1.x, a1.y, a1.z, a1.w};
            float br[8] = {b0.x, b0.y, b0.z, b0.w, b1.x, b1.y, b1.z, b1.w};
#pragma unroll
            for (int i = 0; i < 8; ++i)
#pragma unroll
                for (int j = 0; j < 8; ++j)
                    acc[i][j] += ar[i] * br[j];
        }
    }

#pragma unroll
    for (int i = 0; i < 8; ++i) {
        int r = bm + ((i < 4) ? (ty * 4 + i) : (64 + ty * 4 + i - 4));
#pragma unroll
        for (int jj = 0; jj < 2; ++jj) {
            int c = bn + jj * 64 + tx * 4;
            float4 bb = *(const float4*)&bias[c];
            float4 o;
            o.x = acc[i][jj * 4 + 0] + bb.x;
            o.y = acc[i][jj * 4 + 1] + bb.y;
            o.z = acc[i][jj * 4 + 2] + bb.z;
            o.w = acc[i][jj * 4 + 3] + bb.w;
            *(float4*)&C[(size_t)r * N + c] = o;
        }
    }
}

// Flash-style attention over qkv. One block = (b, h, 64-query block).
// Writes attention output directly in the reference's buggy reshape layout:
//   V2[b, h*64 + s/16, (s%16)*64 + d] = attnout[b,h,s,d]
__global__ __launch_bounds__(256) void attn_kernel(
    const float* __restrict__ qkv, const float* __restrict__ mask,
    float* __restrict__ v2)
{
    __shared__ float Qs[64][68];
    __shared__ float Ks[64][68];
    __shared__ float Vs[64][68];
    __shared__ float Ps[64][68];

    const int tid = threadIdx.x;
    const int tx = tid & 15;   // 0..15
    const int ty = tid >> 4;   // 0..15
    const int qb = blockIdx.x; // 0..15 query block
    const int h  = blockIdx.y; // 0..15
    const int b  = blockIdx.z; // 0..7

    const size_t rowstride = 3 * 1024;
    const float* qbase = qkv + (size_t)b * 1024 * rowstride + (size_t)h * 192;
    const float* kbase = qbase + 64;
    const float* vbase = qbase + 128;
    const float* mrow  = mask + (size_t)(qb * 64) * 1024;

    // Load Q block (pre-scaled by 1/sqrt(HD) = 0.125)
#pragma unroll
    for (int p = 0; p < 4; ++p) {
        int idx = p * 256 + tid;
        int r = idx >> 4;
        int c = (idx & 15) << 2;
        float4 v = *(const float4*)&qbase[(size_t)(qb * 64 + r) * rowstride + c];
        float4 sv; sv.x = v.x * 0.125f; sv.y = v.y * 0.125f;
        sv.z = v.z * 0.125f; sv.w = v.w * 0.125f;
        *(float4*)&Qs[r][c] = sv;
    }

    float m_run[4], l_run[4], acc[4][4];
#pragma unroll
    for (int i = 0; i < 4; ++i) {
        m_run[i] = -1e30f; l_run[i] = 0.f;
#pragma unroll
        for (int j = 0; j < 4; ++j) acc[i][j] = 0.f;
    }

    for (int ch = 0; ch < 16; ++ch) {
        // Issue global loads for K/V chunk first (overlap with barrier)
        float4 kreg[4], vreg[4];
        int rr[4], cc4[4];
#pragma unroll
        for (int p = 0; p < 4; ++p) {
            int idx = p * 256 + tid;
            rr[p] = idx >> 4;
            cc4[p] = (idx & 15) << 2;
            kreg[p] = *(const float4*)&kbase[(size_t)(ch * 64 + rr[p]) * rowstride + cc4[p]];
            vreg[p] = *(const float4*)&vbase[(size_t)(ch * 64 + rr[p]) * rowstride + cc4[p]];
        }

        __syncthreads();  // previous chunk fully consumed

#pragma unroll
        for (int p = 0; p < 4; ++p) {
            *(float4*)&Ks[rr[p]][cc4[p]] = kreg[p];
            *(float4*)&Vs[rr[p]][cc4[p]] = vreg[p];
        }

        __syncthreads();

        // Scores: rows ty*4..+3, cols tx + 16*j (within chunk)
        float s[4][4];
#pragma unroll
        for (int i = 0; i < 4; ++i)
#pragma unroll
            for (int j = 0; j < 4; ++j) s[i][j] = 0.f;

#pragma unroll
        for (int k = 0; k < 64; k += 4) {
            float4 q[4], kk[4];
#pragma unroll
            for (int i = 0; i < 4; ++i) q[i] = *(const float4*)&Qs[ty * 4 + i][k];
#pragma unroll
            for (int j = 0; j < 4; ++j) kk[j] = *(const float4*)&Ks[tx + 16 * j][k];
#pragma unroll
            for (int i = 0; i < 4; ++i)
#pragma unroll
                for (int j = 0; j < 4; ++j)
                    s[i][j] += q[i].x * kk[j].x + q[i].y * kk[j].y +
                               q[i].z * kk[j].z + q[i].w * kk[j].w;
        }

        // Add mask, chunk row-max
        float cmax[4];
#pragma unroll
        for (int i = 0; i < 4; ++i) {
            cmax[i] = -1e30f;
#pragma unroll
            for (int j = 0; j < 4; ++j) {
                s[i][j] += mrow[(size_t)(ty * 4 + i) * 1024 + ch * 64 + tx + 16 * j];
                cmax[i] = fmaxf(cmax[i], s[i][j]);
            }
        }
#pragma unroll
        for (int off = 1; off < 16; off <<= 1)
#pragma unroll
            for (int i = 0; i < 4; ++i)
                cmax[i] = fmaxf(cmax[i], __shfl_xor(cmax[i], off));

        // Online softmax update
        float p[4][4], rsum[4];
#pragma unroll
        for (int i = 0; i < 4; ++i) {
            float mnew = fmaxf(m_run[i], cmax[i]);
            float factor = __expf(m_run[i] - mnew);
            m_run[i] = mnew;
            l_run[i] *= factor;
            rsum[i] = 0.f;
#pragma unroll
            for (int j = 0; j < 4; ++j) {
                p[i][j] = __expf(s[i][j] - mnew);
                rsum[i] += p[i][j];
            }
#pragma unroll
            for (int j = 0; j < 4; ++j) acc[i][j] *= factor;
        }
#pragma unroll
        for (int off = 1; off < 16; off <<= 1)
#pragma unroll
            for (int i = 0; i < 4; ++i)
                rsum[i] += __shfl_xor(rsum[i], off);
#pragma unroll
        for (int i = 0; i < 4; ++i) l_run[i] += rsum[i];

        // Stage P
#pragma unroll
        for (int i = 0; i < 4; ++i)
#pragma unroll
            for (int j = 0; j < 4; ++j)
                Ps[ty * 4 + i][tx + 16 * j] = p[i][j];

        __syncthreads();

        // PV: acc[i][j] += sum_k P[r][k] * V[k][tx*4+j]
#pragma unroll
        for (int k = 0; k < 64; k += 4) {
            float4 pr[4], vv[4];
#pragma unroll
            for (int i = 0; i < 4; ++i) pr[i] = *(const float4*)&Ps[ty * 4 + i][k];
#pragma unroll
            for (int m = 0; m < 4; ++m) vv[m] = *(const float4*)&Vs[k + m][tx * 4];
#pragma unroll
            for (int i = 0; i < 4; ++i) {
                acc[i][0] += pr[i].x * vv[0].x + pr[i].y * vv[1].x + pr[i].z * vv[2].x + pr[i].w * vv[3].x;
                acc[i][1] += pr[i].x * vv[0].y + pr[i].y * vv[1].y + pr[i].z * vv[2].y + pr[i].w * vv[3].y;
                acc[i][2] += pr[i].x * vv[0].z + pr[i].y * vv[1].z + pr[i].z * vv[2].z + pr[i].w * vv[3].z;
                acc[i][3] += pr[i].x * vv[0].w + pr[i].y * vv[1].w + pr[i].z * vv[2].w + pr[i].w * vv[3].w;
            }
        }
        // next iteration's first barrier protects Ks/Vs/Ps overwrite
    }

    // Epilogue: normalize and scatter into buggy-reshape layout
#pragma unroll
    for (int i = 0; i < 4; ++i) {
        float inv = 1.f / l_run[i];
        int s_ = qb * 64 + ty * 4 + i;
        size_t base = (size_t)b * 1024 * 1024 +
                      (size_t)(h * 64 + (s_ >> 4)) * 1024 +
                      (size_t)((s_ & 15) << 6);
        float4 o;
        o.x = acc[i][0] * inv; o.y = acc[i][1] * inv;
        o.z = acc[i][2] * inv; o.w = acc[i][3] * inv;
        *(float4*)&v2[base + tx * 4] = o;
    }
}

extern "C" void kernel_launch(void* const* d_in, const int* in_sizes, int n_in,
                              void* d_out, int out_size, void* d_ws, size_t ws_size,
                              hipStream_t stream)
{
    const float* x    = (const float*)d_in[0];
    const float* mask = (const float*)d_in[1];
    const float* Wqkv = (const float*)d_in[2];
    const float* bqkv = (const float*)d_in[3];
    const float* Wo   = (const float*)d_in[4];
    const float* bo   = (const float*)d_in[5];
    float* out = (float*)d_out;

    float* qkv = (float*)d_ws;                          // 8192 x 3072
    float* v2  = qkv + (size_t)8192 * 3072;             // 8192 x 1024

    dim3 blk(256);
    // QKV projection: M=8192, N=3072, K=1024
    gemm_nt_bias<<<dim3(3072 / BN, 8192 / BM), blk, 0, stream>>>(
        x, Wqkv, bqkv, qkv, 8192, 3072, 1024);
    // Attention: (qblock, head, batch)
    attn_kernel<<<dim3(16, 16, 8), blk, 0, stream>>>(qkv, mask, v2);
    // Output projection: M=8192, N=1024, K=1024
    gemm_nt_bias<<<dim3(1024 / BN, 8192 / BM), blk, 0, stream>>>(
        v2, Wo, bo, out, 8192, 1024, 1024);
}

// Round 3
// 797.218 us; speedup vs baseline: 2.9162x; 2.9162x over previous
//
#include <hip/hip_runtime.h>
#include <math.h>

// B=8, S=1024, D=1024, H=16, HD=64.  M = B*S = 8192 tokens.
// Strategy: split-bf16 (hi+lo) MFMA everywhere.
//   C = Ah*Bh + Ah*Bl + Al*Bh  ==  plain bf16 GEMM over K' = 3K with
//   A' = [Ah|Ah|Al], B' = [Bh|Bl|Bh].
// GEMM1: qkv = x @ Wqkv^T + bqkv  (A=x fp32 converted on the fly, B=Wqkv' tripled)
//        epilogue stores qkv_hi (bf16) and qk_lo (bf16, q/k cols only).
// attn : MFMA flash attention, split Q/K scores (K'=192), plain bf16 P,V.
//        epilogue writes V2' = [hi|lo] bf16 in the reference's buggy reshape layout.
// GEMM2: out = V2 @ Wo^T + bo  (A=V2' [hi|lo] with piecewise region map, B=Wo' tripled)

typedef __attribute__((ext_vector_type(8))) short short8v;
typedef __attribute__((ext_vector_type(4))) float floatx4;

__device__ inline unsigned short f2bf(float f) {
    return __builtin_bit_cast(unsigned short, (__bf16)f);
}
__device__ inline float bf2f(unsigned short u) {
    return (float)__builtin_bit_cast(__bf16, u);
}

__device__ inline void gload_lds16(const void* g, void* l) {
    __builtin_amdgcn_global_load_lds((const __attribute__((address_space(1))) void*)g,
                                     (__attribute__((address_space(3))) void*)l,
                                     16, 0, 0);
}

// ---------------- conversion: W [N][1024] fp32 -> W' [N][3072] bf16 [hi|lo|hi]
__global__ __launch_bounds__(256) void conv_w_tripled(
    const float* __restrict__ W, unsigned short* __restrict__ Wp, int total)
{
    int i = (blockIdx.x * 256 + threadIdx.x) * 4;
    if (i >= total) return;
    int row = i >> 10, c = i & 1023;
    float4 v = *(const float4*)&W[i];
    float f[4] = {v.x, v.y, v.z, v.w};
    unsigned short hs[4], ls[4];
#pragma unroll
    for (int j = 0; j < 4; ++j) {
        hs[j] = f2bf(f[j]);
        ls[j] = f2bf(f[j] - bf2f(hs[j]));
    }
    ushort4 h4 = {hs[0], hs[1], hs[2], hs[3]};
    ushort4 l4 = {ls[0], ls[1], ls[2], ls[3]};
    size_t base = (size_t)row * 3072;
    *(ushort4*)&Wp[base + c] = h4;
    *(ushort4*)&Wp[base + 1024 + c] = l4;
    *(ushort4*)&Wp[base + 2048 + c] = h4;
}

// ---------------- GEMM1: qkv projection, M=8192 N=3072 K'=3072
__global__ __launch_bounds__(256) void gemm1_qkv(
    const float* __restrict__ X,              // [8192][1024] fp32
    const unsigned short* __restrict__ Wp,    // [3072][3072] bf16 tripled
    const float* __restrict__ bias,           // [3072]
    unsigned short* __restrict__ qkv_hi,      // [8192][3072] bf16
    unsigned short* __restrict__ qk_lo)       // [8192][2048] bf16 (per head: q_lo 64 | k_lo 64)
{
    __shared__ unsigned short As[128 * 32];   // 8KB, row-major [128][32]
    __shared__ unsigned short Bs[128 * 32];   // 8KB

    const int tid = threadIdx.x;
    const int lane = tid & 63, wave = tid >> 6;
    const int wr = wave >> 1, wc = wave & 1;
    const int bm = blockIdx.y * 128, bn = blockIdx.x * 128;

    floatx4 acc[4][4] = {};

    const int ar0 = tid >> 2;         // 0..63
    const int ak  = (tid & 3) * 8;    // 0,8,16,24

    for (int k0 = 0; k0 < 3072; k0 += 32) {
        const int region = k0 >> 10;        // 0,1 -> hi(x); 2 -> lo(x)
        const int ksrc = k0 & 1023;

        // A source loads (fp32), rows ar0 and ar0+64, 8 cols each
        float4 a0 = *(const float4*)&X[(size_t)(bm + ar0) * 1024 + ksrc + ak];
        float4 a1 = *(const float4*)&X[(size_t)(bm + ar0) * 1024 + ksrc + ak + 4];
        float4 a2 = *(const float4*)&X[(size_t)(bm + ar0 + 64) * 1024 + ksrc + ak];
        float4 a3 = *(const float4*)&X[(size_t)(bm + ar0 + 64) * 1024 + ksrc + ak + 4];

        __syncthreads();  // previous iter's LDS reads complete

        // B tile via global_load_lds: linear [128][64B], wave-chunked
#pragma unroll
        for (int c = 0; c < 2; ++c) {
            int o = wave * 2048 + c * 1024 + lane * 16;   // byte offset in tile
            int brow = o >> 6, bcol = o & 63;
            const unsigned short* gsrc = Wp + (size_t)(bn + brow) * 3072 + k0 + (bcol >> 1);
            gload_lds16(gsrc, (char*)Bs + o);
        }

        // A tile: convert fp32 -> bf16 (hi or lo) and ds_write contiguously
        {
            float ff0[8] = {a0.x, a0.y, a0.z, a0.w, a1.x, a1.y, a1.z, a1.w};
            float ff1[8] = {a2.x, a2.y, a2.z, a2.w, a3.x, a3.y, a3.z, a3.w};
            unsigned short t0[8], t1[8];
            if (region < 2) {
#pragma unroll
                for (int j = 0; j < 8; ++j) { t0[j] = f2bf(ff0[j]); t1[j] = f2bf(ff1[j]); }
            } else {
#pragma unroll
                for (int j = 0; j < 8; ++j) {
                    unsigned short h0 = f2bf(ff0[j]); t0[j] = f2bf(ff0[j] - bf2f(h0));
                    unsigned short h1 = f2bf(ff1[j]); t1[j] = f2bf(ff1[j] - bf2f(h1));
                }
            }
            *(short8v*)((char*)As + tid * 16)        = *(short8v*)t0;  // rows 0..63
            *(short8v*)((char*)As + 4096 + tid * 16) = *(short8v*)t1;  // rows 64..127
        }

        __syncthreads();  // drains ds_write + global_load_lds

        short8v af[4], bf[4];
#pragma unroll
        for (int m = 0; m < 4; ++m)
            af[m] = *(short8v*)((char*)As + (wr * 64 + m * 16 + (lane & 15)) * 64 + (lane >> 4) * 16);
#pragma unroll
        for (int n = 0; n < 4; ++n)
            bf[n] = *(short8v*)((char*)Bs + (wc * 64 + n * 16 + (lane & 15)) * 64 + (lane >> 4) * 16);
#pragma unroll
        for (int m = 0; m < 4; ++m)
#pragma unroll
            for (int n = 0; n < 4; ++n)
                acc[m][n] = __builtin_amdgcn_mfma_f32_16x16x32_bf16(af[m], bf[n], acc[m][n], 0, 0, 0);
    }

    // Epilogue: C/D layout col=lane&15, row=(lane>>4)*4+reg
#pragma unroll
    for (int n = 0; n < 4; ++n) {
        int col = bn + wc * 64 + n * 16 + (lane & 15);
        float bb = bias[col];
        int hh = col / 192, within = col % 192;
#pragma unroll
        for (int m = 0; m < 4; ++m)
#pragma unroll
            for (int j = 0; j < 4; ++j) {
                int row = bm + wr * 64 + m * 16 + (lane >> 4) * 4 + j;
                float val = acc[m][n][j] + bb;
                unsigned short h = f2bf(val);
                qkv_hi[(size_t)row * 3072 + col] = h;
                if (within < 128)
                    qk_lo[(size_t)row * 2048 + hh * 128 + within] = f2bf(val - bf2f(h));
            }
    }
}

// ---------------- attention: MFMA flash, grid (16 qblocks, 16 heads, 8 batch)
#define QP 200   // Q'/K' LDS row stride (elems): 400B -> 2-way-bank-safe
#define VP 72    // VT/P LDS row stride: 144B -> 2-way-bank-safe

__global__ __launch_bounds__(256) void attn_mfma(
    const unsigned short* __restrict__ qkv_hi,  // [8192][3072]
    const unsigned short* __restrict__ qk_lo,   // [8192][2048]
    const float* __restrict__ mask,             // [1024][1024]
    unsigned short* __restrict__ V2p)           // [8192][2048] = [hi|lo]
{
    __shared__ unsigned short Qs[64 * QP];   // 25.6KB: [Qh|Qh|Ql] * 0.125
    __shared__ unsigned short Ks[64 * QP];   // 25.6KB: [Kh|Kl|Kh]
    __shared__ unsigned short VT[64 * VP];   // 9.2KB : V^T  [d][k]
    __shared__ unsigned short Ps[64 * VP];   // 9.2KB : P    [q][k]

    const int tid = threadIdx.x, lane = tid & 63, wave = tid >> 6;
    const int qb = blockIdx.x, h = blockIdx.y, b = blockIdx.z;
    const size_t hi_base = (size_t)b * 1024 * 3072;
    const size_t lo_base = (size_t)b * 1024 * 2048;
    const int hq = h * 192, hk = h * 192 + 64, hv = h * 192 + 128;
    const int lq = h * 128, lk = h * 128 + 64;

    // ---- stage Q' (once): cols [0,64)=0.125*Qh, [64,128)=0.125*Qh, [128,192)=0.125*Ql
    for (int c = tid; c < 64 * 24; c += 256) {
        int r = c / 24, k8 = (c % 24) * 8;
        ushort4 u0, u1;
        if (k8 < 128) {
            int kk = k8 & 63;
            const unsigned short* s = qkv_hi + hi_base + (size_t)(qb * 64 + r) * 3072 + hq + kk;
            u0 = *(const ushort4*)&s[0]; u1 = *(const ushort4*)&s[4];
        } else {
            int kk = k8 - 128;
            const unsigned short* s = qk_lo + lo_base + (size_t)(qb * 64 + r) * 2048 + lq + kk;
            u0 = *(const ushort4*)&s[0]; u1 = *(const ushort4*)&s[4];
        }
        unsigned short raw[8], sc8[8];
        *(ushort4*)&raw[0] = u0; *(ushort4*)&raw[4] = u1;
#pragma unroll
        for (int j = 0; j < 8; ++j) sc8[j] = f2bf(bf2f(raw[j]) * 0.125f);  // exact pow2 scale
        *(short8v*)&Qs[r * QP + k8] = *(short8v*)sc8;
    }

    float m_run[4] = {-3e38f, -3e38f, -3e38f, -3e38f};
    float l_run[4] = {0.f, 0.f, 0.f, 0.f};
    floatx4 accv[4] = {};

    for (int ch = 0; ch < 16; ++ch) {
        __syncthreads();  // prev chunk LDS reads complete

        // ---- stage K' : [Kh|Kl|Kh]
        for (int c = tid; c < 64 * 24; c += 256) {
            int r = c / 24, k8 = (c % 24) * 8;
            ushort4 u0, u1;
            if (k8 < 64 || k8 >= 128) {
                int kk = (k8 >= 128) ? (k8 - 128) : k8;
                const unsigned short* s = qkv_hi + hi_base + (size_t)(ch * 64 + r) * 3072 + hk + kk;
                u0 = *(const ushort4*)&s[0]; u1 = *(const ushort4*)&s[4];
            } else {
                int kk = k8 - 64;
                const unsigned short* s = qk_lo + lo_base + (size_t)(ch * 64 + r) * 2048 + lk + kk;
                u0 = *(const ushort4*)&s[0]; u1 = *(const ushort4*)&s[4];
            }
            unsigned short t8[8];
            *(ushort4*)&t8[0] = u0; *(ushort4*)&t8[4] = u1;
            *(short8v*)&Ks[r * QP + k8] = *(short8v*)t8;
        }
        // ---- stage V^T (plain bf16 hi)
        {
            int kr = tid >> 2, d0 = (tid & 3) * 16;
            const unsigned short* vsrc = qkv_hi + hi_base + (size_t)(ch * 64 + kr) * 3072 + hv + d0;
            unsigned short vv[16];
            *(ushort4*)&vv[0]  = *(const ushort4*)&vsrc[0];
            *(ushort4*)&vv[4]  = *(const ushort4*)&vsrc[4];
            *(ushort4*)&vv[8]  = *(const ushort4*)&vsrc[8];
            *(ushort4*)&vv[12] = *(const ushort4*)&vsrc[12];
#pragma unroll
            for (int j = 0; j < 16; ++j) VT[(d0 + j) * VP + kr] = vv[j];
        }

        __syncthreads();

        // ---- scores: wave's 16 q-rows x 64 keys, K'=192
        floatx4 sc[4] = {};
#pragma unroll
        for (int ks = 0; ks < 6; ++ks) {
            short8v a = *(short8v*)&Qs[(wave * 16 + (lane & 15)) * QP + ks * 32 + (lane >> 4) * 8];
#pragma unroll
            for (int n = 0; n < 4; ++n) {
                short8v bb = *(short8v*)&Ks[(n * 16 + (lane & 15)) * QP + ks * 32 + (lane >> 4) * 8];
                sc[n] = __builtin_amdgcn_mfma_f32_16x16x32_bf16(a, bb, sc[n], 0, 0, 0);
            }
        }

        // ---- softmax (online), C layout: col=lane&15, row=(lane>>4)*4+j
        const float* mrow = mask + (size_t)(qb * 64 + wave * 16) * 1024 + ch * 64;
        float sv[4][4];
        float cmax[4] = {-3e38f, -3e38f, -3e38f, -3e38f};
#pragma unroll
        for (int j = 0; j < 4; ++j)
#pragma unroll
            for (int n = 0; n < 4; ++n) {
                float val = sc[n][j] + mrow[((lane >> 4) * 4 + j) * 1024 + n * 16 + (lane & 15)];
                sv[n][j] = val;
                cmax[j] = fmaxf(cmax[j], val);
            }
#pragma unroll
        for (int off = 1; off < 16; off <<= 1)
#pragma unroll
            for (int j = 0; j < 4; ++j)
                cmax[j] = fmaxf(cmax[j], __shfl_xor(cmax[j], off));

        float fct[4], rsum[4];
#pragma unroll
        for (int j = 0; j < 4; ++j) {
            float mnew = fmaxf(m_run[j], cmax[j]);
            fct[j] = __expf(m_run[j] - mnew);
            m_run[j] = mnew;
            rsum[j] = 0.f;
#pragma unroll
            for (int n = 0; n < 4; ++n) {
                float p = __expf(sv[n][j] - mnew);
                rsum[j] += p;
                Ps[(wave * 16 + (lane >> 4) * 4 + j) * VP + n * 16 + (lane & 15)] = f2bf(p);
            }
        }
#pragma unroll
        for (int off = 1; off < 16; off <<= 1)
#pragma unroll
            for (int j = 0; j < 4; ++j)
                rsum[j] += __shfl_xor(rsum[j], off);
#pragma unroll
        for (int j = 0; j < 4; ++j) l_run[j] = l_run[j] * fct[j] + rsum[j];
#pragma unroll
        for (int n = 0; n < 4; ++n)
#pragma unroll
            for (int j = 0; j < 4; ++j)
                accv[n][j] *= fct[j];

        // ---- PV: A = P rows (this wave's 16 q), B = VT rows (d)
#pragma unroll
        for (int ks = 0; ks < 2; ++ks) {
            short8v a = *(short8v*)&Ps[(wave * 16 + (lane & 15)) * VP + ks * 32 + (lane >> 4) * 8];
#pragma unroll
            for (int n = 0; n < 4; ++n) {
                short8v bb = *(short8v*)&VT[(n * 16 + (lane & 15)) * VP + ks * 32 + (lane >> 4) * 8];
                accv[n] = __builtin_amdgcn_mfma_f32_16x16x32_bf16(a, bb, accv[n], 0, 0, 0);
            }
        }
    }

    // ---- epilogue: normalize, write V2' [hi|lo] in buggy-reshape layout
#pragma unroll
    for (int j = 0; j < 4; ++j) {
        float inv = 1.f / l_run[j];
        int s_ = qb * 64 + wave * 16 + (lane >> 4) * 4 + j;
        size_t row2 = (size_t)(b * 1024 + h * 64 + (s_ >> 4)) * 2048;
        int colh = (s_ & 15) * 64;
#pragma unroll
        for (int n = 0; n < 4; ++n) {
            int d = n * 16 + (lane & 15);
            float val = accv[n][j] * inv;
            unsigned short hh2 = f2bf(val);
            V2p[row2 + colh + d] = hh2;
            V2p[row2 + 1024 + colh + d] = f2bf(val - bf2f(hh2));
        }
    }
}

// ---------------- GEMM2: out projection, M=8192 N=1024 K'=3072
__global__ __launch_bounds__(256) void gemm2_out(
    const unsigned short* __restrict__ V2,    // [8192][2048] = [hi|lo]
    const unsigned short* __restrict__ Wop,   // [1024][3072] tripled
    const float* __restrict__ bias,           // [1024]
    float* __restrict__ Out)                  // [8192][1024]
{
    __shared__ unsigned short As[128 * 32];
    __shared__ unsigned short Bs[128 * 32];

    const int tid = threadIdx.x;
    const int lane = tid & 63, wave = tid >> 6;
    const int wr = wave >> 1, wc = wave & 1;
    const int bm = blockIdx.y * 128, bn = blockIdx.x * 128;

    floatx4 acc[4][4] = {};

    for (int k0 = 0; k0 < 3072; k0 += 32) {
        const int region = k0 >> 10;
        const int acolbase = (region == 2 ? 1024 : 0) + (k0 & 1023);

        __syncthreads();

#pragma unroll
        for (int c = 0; c < 2; ++c) {
            int o = wave * 2048 + c * 1024 + lane * 16;
            int row = o >> 6, colb = o & 63;
            const unsigned short* ga = V2 + (size_t)(bm + row) * 2048 + acolbase + (colb >> 1);
            gload_lds16(ga, (char*)As + o);
            const unsigned short* gb = Wop + (size_t)(bn + row) * 3072 + k0 + (colb >> 1);
            gload_lds16(gb, (char*)Bs + o);
        }

        __syncthreads();

        short8v af[4], bf[4];
#pragma unroll
        for (int m = 0; m < 4; ++m)
            af[m] = *(short8v*)((char*)As + (wr * 64 + m * 16 + (lane & 15)) * 64 + (lane >> 4) * 16);
#pragma unroll
        for (int n = 0; n < 4; ++n)
            bf[n] = *(short8v*)((char*)Bs + (wc * 64 + n * 16 + (lane & 15)) * 64 + (lane >> 4) * 16);
#pragma unroll
        for (int m = 0; m < 4; ++m)
#pragma unroll
            for (int n = 0; n < 4; ++n)
                acc[m][n] = __builtin_amdgcn_mfma_f32_16x16x32_bf16(af[m], bf[n], acc[m][n], 0, 0, 0);
    }

#pragma unroll
    for (int n = 0; n < 4; ++n) {
        int col = bn + wc * 64 + n * 16 + (lane & 15);
        float bb = bias[col];
#pragma unroll
        for (int m = 0; m < 4; ++m)
#pragma unroll
            for (int j = 0; j < 4; ++j) {
                int row = bm + wr * 64 + m * 16 + (lane >> 4) * 4 + j;
                Out[(size_t)row * 1024 + col] = acc[m][n][j] + bb;
            }
    }
}

extern "C" void kernel_launch(void* const* d_in, const int* in_sizes, int n_in,
                              void* d_out, int out_size, void* d_ws, size_t ws_size,
                              hipStream_t stream)
{
    const float* x    = (const float*)d_in[0];
    const float* mask = (const float*)d_in[1];
    const float* Wqkv = (const float*)d_in[2];
    const float* bqkv = (const float*)d_in[3];
    const float* Wo   = (const float*)d_in[4];
    const float* bo   = (const float*)d_in[5];
    float* out = (float*)d_out;

    // workspace layout (peak 118MB; round-1 run proved >=128MB available):
    char* w = (char*)d_ws;
    unsigned short* qkv_hi = (unsigned short*)w;                         // 48MB
    unsigned short* qk_lo  = (unsigned short*)(w + 50331648);            // 32MB
    unsigned short* Wp     = (unsigned short*)(w + 50331648 + 33554432); // 18.9MB (region R)
    unsigned short* V2p    = Wp;                                         // 32MB, aliases Wp (dead after gemm1)
    unsigned short* Wop    = (unsigned short*)(w + 50331648 + 33554432 + 33554432); // 6MB

    conv_w_tripled<<<3072, 256, 0, stream>>>(Wqkv, Wp, 3072 * 1024);
    conv_w_tripled<<<1024, 256, 0, stream>>>(Wo, Wop, 1024 * 1024);

    gemm1_qkv<<<dim3(24, 64), 256, 0, stream>>>(x, Wp, bqkv, qkv_hi, qk_lo);

    attn_mfma<<<dim3(16, 16, 8), 256, 0, stream>>>(qkv_hi, qk_lo, mask, V2p);

    gemm2_out<<<dim3(8, 64), 256, 0, stream>>>(V2p, Wop, bo, out);
}

// Round 5
// 530.495 us; speedup vs baseline: 4.3825x; 1.5028x over previous
//
#include <hip/hip_runtime.h>
#include <math.h>

// B=8, S=1024, D=1024, H=16, HD=64.  M = B*S = 8192 tokens.
// Split-bf16 (hi+lo) MFMA everywhere: C = Ah*Bh + Ah*Bl + Al*Bh via K'=3072
// with piecewise region maps over [h|l]-paired operands.
// gemm1: qkv = x @ Wqkv^T + b  (A = Xp=[Xh|Xl], B = Wp=[Wh|Wl]); epilogue
//        stores qkv_hi (q pre-scaled by 0.125) + qk_lo (q/k lo parts, q scaled).
// attn : swapped-QK MFMA flash attention (Q hoisted to regs), swizzled LDS.
// gemm2: out = V2 @ Wo^T + bo (A = V2p=[hi|lo], B = Wop=[h|l]).

typedef __attribute__((ext_vector_type(8))) short short8v;
typedef __attribute__((ext_vector_type(4))) float floatx4;

__device__ inline unsigned short f2bf(float f) {
    return __builtin_bit_cast(unsigned short, (__bf16)f);
}
__device__ inline float bf2f(unsigned short u) {
    return (float)__builtin_bit_cast(__bf16, u);
}

__device__ inline void gload_lds16(const void* g, void* l) {
    __builtin_amdgcn_global_load_lds((const __attribute__((address_space(1))) void*)g,
                                     (__attribute__((address_space(3))) void*)l,
                                     16, 0, 0);
}

// ---------------- split fp32 [N][1024] -> bf16 [N][2048] = [hi|lo]
__global__ __launch_bounds__(256) void conv_split(
    const float* __restrict__ W, unsigned short* __restrict__ Wp)
{
    int i = (blockIdx.x * 256 + threadIdx.x) * 4;
    int row = i >> 10, c = i & 1023;
    float4 v = *(const float4*)&W[i];
    float f[4] = {v.x, v.y, v.z, v.w};
    unsigned short hs[4], ls[4];
#pragma unroll
    for (int j = 0; j < 4; ++j) {
        hs[j] = f2bf(f[j]);
        ls[j] = f2bf(f[j] - bf2f(hs[j]));
    }
    ushort4 h4 = {hs[0], hs[1], hs[2], hs[3]};
    ushort4 l4 = {ls[0], ls[1], ls[2], ls[3]};
    size_t base = (size_t)row * 2048;
    *(ushort4*)&Wp[base + c] = h4;
    *(ushort4*)&Wp[base + 1024 + c] = l4;
}

// ---------------- GEMM1: qkv projection, M=8192 N=3072 K'=3072
__global__ __launch_bounds__(256) void gemm1_qkv(
    const unsigned short* __restrict__ Xp,    // [8192][2048] = [Xh|Xl]
    const unsigned short* __restrict__ Wp,    // [3072][2048] = [Wh|Wl]
    const float* __restrict__ bias,           // [3072]
    unsigned short* __restrict__ qkv_hi,      // [8192][3072]; q cols pre-scaled 0.125
    unsigned short* __restrict__ qk_lo)       // [8192][2048] per head: q_lo(64)|k_lo(64)
{
    __shared__ unsigned short As[128 * 32];   // 8KB [128][32]
    __shared__ unsigned short Bs[128 * 32];

    const int tid = threadIdx.x;
    const int lane = tid & 63, wave = tid >> 6;
    const int wr = wave >> 1, wc = wave & 1;
    // XCD-aware swizzle: grid (24, 64) -> 1536 = 8 * 192
    const int wg = blockIdx.y * 24 + blockIdx.x;
    const int swz = (wg & 7) * 192 + (wg >> 3);
    const int bm = (swz / 24) * 128, bn = (swz % 24) * 128;

    floatx4 acc[4][4] = {};

    for (int k0 = 0; k0 < 3072; k0 += 32) {
        const int region = k0 >> 10;
        const int acol = ((region == 2) ? 1024 : 0) + (k0 & 1023);
        const int bcol = ((region == 1) ? 1024 : 0) + (k0 & 1023);

        __syncthreads();

#pragma unroll
        for (int c = 0; c < 2; ++c) {
            int o = wave * 2048 + c * 1024 + lane * 16;   // byte offset in tile
            int row = o >> 6, ce = (o & 63) >> 1;         // ce: elem offset 0..31
            gload_lds16(Xp + (size_t)(bm + row) * 2048 + acol + ce, (char*)As + o);
            gload_lds16(Wp + (size_t)(bn + row) * 2048 + bcol + ce, (char*)Bs + o);
        }

        __syncthreads();

        short8v af[4], bf[4];
#pragma unroll
        for (int m = 0; m < 4; ++m)
            af[m] = *(short8v*)((char*)As + (wr * 64 + m * 16 + (lane & 15)) * 64 + (lane >> 4) * 16);
#pragma unroll
        for (int n = 0; n < 4; ++n)
            bf[n] = *(short8v*)((char*)Bs + (wc * 64 + n * 16 + (lane & 15)) * 64 + (lane >> 4) * 16);
#pragma unroll
        for (int m = 0; m < 4; ++m)
#pragma unroll
            for (int n = 0; n < 4; ++n)
                acc[m][n] = __builtin_amdgcn_mfma_f32_16x16x32_bf16(af[m], bf[n], acc[m][n], 0, 0, 0);
    }

    // Epilogue: C/D layout col=lane&15, row=(lane>>4)*4+j.  q cols scaled 0.125.
#pragma unroll
    for (int n = 0; n < 4; ++n) {
        int col = bn + wc * 64 + n * 16 + (lane & 15);
        float bb = bias[col];
        int hh = col / 192, within = col % 192;
#pragma unroll
        for (int m = 0; m < 4; ++m)
#pragma unroll
            for (int j = 0; j < 4; ++j) {
                int row = bm + wr * 64 + m * 16 + (lane >> 4) * 4 + j;
                float val = acc[m][n][j] + bb;
                if (within < 64) {                // q: pre-scale by 1/sqrt(64)
                    float vs = val * 0.125f;
                    unsigned short h = f2bf(vs);
                    qkv_hi[(size_t)row * 3072 + col] = h;
                    qk_lo[(size_t)row * 2048 + hh * 128 + within] = f2bf(vs - bf2f(h));
                } else if (within < 128) {        // k
                    unsigned short h = f2bf(val);
                    qkv_hi[(size_t)row * 3072 + col] = h;
                    qk_lo[(size_t)row * 2048 + hh * 128 + within] = f2bf(val - bf2f(h));
                } else {                          // v
                    qkv_hi[(size_t)row * 3072 + col] = f2bf(val);
                }
            }
    }
}

// ---------------- attention v2: swapped-QK MFMA flash, grid (16, 16, 8)
#define QP 200   // Ks row stride (elems)
#define VP 72    // VT / Ps row stride (elems)
#define MP 65    // msT q-stride (f32)

__global__ __launch_bounds__(256) void attn_mfma2(
    const unsigned short* __restrict__ qkv_hi,  // [8192][3072] (q scaled)
    const unsigned short* __restrict__ qk_lo,   // [8192][2048] (q_lo scaled)
    const float* __restrict__ mask,             // [1024][1024]
    unsigned short* __restrict__ V2p)           // [8192][2048] = [hi|lo]
{
    __shared__ unsigned short Ks[64 * QP];   // 25.6KB [Kh|Kl|Kh]
    __shared__ unsigned short VT[64 * VP];   // 9.2KB  V^T swizzled
    __shared__ unsigned short Ps[64 * VP];   // 9.2KB  P swizzled
    __shared__ float msT[64 * MP];           // 16.6KB mask^T chunk [k][q]

    const int tid = threadIdx.x, lane = tid & 63, w = tid >> 6;
    const int i = lane & 15, lg = lane >> 4;
    const int qb = blockIdx.x, h = blockIdx.y, b = blockIdx.z;
    const size_t hi_base = (size_t)b * 1024 * 3072;
    const size_t lo_base = (size_t)b * 1024 * 2048;
    const int hq = h * 192, hk = h * 192 + 64, hv = h * 192 + 128;
    const int lq = h * 128, lk = h * 128 + 64;

    // ---- hoist Q' into registers (B-frag layout). cols: [Qh|Qh|Ql], all scaled.
    short8v qf[6];
    {
        const int qrow = qb * 64 + w * 16 + i;
#pragma unroll
        for (int ks = 0; ks < 6; ++ks) {
            int c = ks * 32 + lg * 8;
            const unsigned short* src = (c < 128)
                ? qkv_hi + hi_base + (size_t)qrow * 3072 + hq + (c & 63)
                : qk_lo + lo_base + (size_t)qrow * 2048 + lq + (c - 128);
            qf[ks] = *(const short8v*)src;
        }
    }

    // staging registers
    short8v kreg[6], vreg[2];
    float4 mreg[4];
    const int kr = tid >> 2, d0 = (tid & 3) * 16;   // V staging coords

    auto load_ch = [&](int ch) {
#pragma unroll
        for (int p = 0; p < 6; ++p) {
            int c = p * 256 + tid;
            int r = c / 24, k8 = (c % 24) * 8;
            const unsigned short* s;
            if (k8 < 64)       s = qkv_hi + hi_base + (size_t)(ch * 64 + r) * 3072 + hk + k8;
            else if (k8 < 128) s = qk_lo + lo_base + (size_t)(ch * 64 + r) * 2048 + lk + (k8 - 64);
            else               s = qkv_hi + hi_base + (size_t)(ch * 64 + r) * 3072 + hk + (k8 - 128);
            kreg[p] = *(const short8v*)s;
        }
        const unsigned short* vsrc = qkv_hi + hi_base + (size_t)(ch * 64 + kr) * 3072 + hv + d0;
        vreg[0] = *(const short8v*)vsrc;
        vreg[1] = *(const short8v*)(vsrc + 8);
#pragma unroll
        for (int p = 0; p < 4; ++p) {
            int idx = p * 256 + tid;
            mreg[p] = *(const float4*)&mask[(size_t)(qb * 64 + (idx >> 4)) * 1024 + ch * 64 + (idx & 15) * 4];
        }
    };

    auto write_ch = [&]() {
#pragma unroll
        for (int p = 0; p < 6; ++p) {
            int c = p * 256 + tid;
            int r = c / 24, k8 = (c % 24) * 8;
            *(short8v*)&Ks[r * QP + k8] = kreg[p];
        }
        // V^T with kh ^= (d>>3)&7 swizzle (2-way banks both sides)
        {
            unsigned kh = kr >> 3, klo = kr & 7;
#pragma unroll
            for (int j = 0; j < 16; ++j) {
                unsigned short vv = (j < 8) ? (unsigned short)vreg[0][j] : (unsigned short)vreg[1][j - 8];
                int d = d0 + j;
                VT[d * VP + ((kh ^ ((d >> 3) & 7)) * 8 + klo)] = vv;
            }
        }
#pragma unroll
        for (int p = 0; p < 4; ++p) {
            int idx = p * 256 + tid;
            int q = idx >> 4, k4 = (idx & 15) * 4;
            msT[(k4 + 0) * MP + q] = mreg[p].x;
            msT[(k4 + 1) * MP + q] = mreg[p].y;
            msT[(k4 + 2) * MP + q] = mreg[p].z;
            msT[(k4 + 3) * MP + q] = mreg[p].w;
        }
    };

    load_ch(0);
    float m_run = -3e30f, l_run = 0.f;
    floatx4 accv[4] = {};
    const unsigned qsw = ((w * 16 + i) >> 2) & 7;   // Ps swizzle key (own q)

    for (int ch = 0; ch < 16; ++ch) {
        __syncthreads();       // previous compute done reading Ks/VT/msT
        write_ch();
        __syncthreads();       // staging visible
        if (ch < 15) load_ch(ch + 1);   // prefetch next chunk under compute

        // ---- scores S^T[k][q]: mfma(A=K from LDS, B=Q from regs)
        floatx4 sc[4] = {};
#pragma unroll
        for (int ks = 0; ks < 6; ++ks) {
#pragma unroll
            for (int n = 0; n < 4; ++n) {
                short8v kf = *(const short8v*)&Ks[(n * 16 + i) * QP + ks * 32 + lg * 8];
                sc[n] = __builtin_amdgcn_mfma_f32_16x16x32_bf16(kf, qf[ks], sc[n], 0, 0, 0);
            }
        }

        // ---- mask add + lane-local softmax (lane owns q = w*16+i; k = n*16+lg*4+r)
        float sv[4][4];
        float cmax = -3e30f;
#pragma unroll
        for (int n = 0; n < 4; ++n)
#pragma unroll
            for (int r = 0; r < 4; ++r) {
                float val = sc[n][r] + msT[(n * 16 + lg * 4 + r) * MP + w * 16 + i];
                sv[n][r] = val;
                cmax = fmaxf(cmax, val);
            }
        cmax = fmaxf(cmax, __shfl_xor(cmax, 16));
        cmax = fmaxf(cmax, __shfl_xor(cmax, 32));

        float mnew = fmaxf(m_run, cmax);
        float fct = __expf(m_run - mnew);
        m_run = mnew;
        float rsum = 0.f;
        float pv[4][4];
#pragma unroll
        for (int n = 0; n < 4; ++n)
#pragma unroll
            for (int r = 0; r < 4; ++r) {
                float pp = __expf(sv[n][r] - mnew);
                pv[n][r] = pp;
                rsum += pp;
            }
        rsum += __shfl_xor(rsum, 16);
        rsum += __shfl_xor(rsum, 32);
        l_run = l_run * fct + rsum;

        // rescale accv: its q = w*16 + lg*4 + reg -> fct from lane (lg*4+reg)
        float fr[4];
#pragma unroll
        for (int r = 0; r < 4; ++r) fr[r] = __shfl(fct, lg * 4 + r);
#pragma unroll
        for (int n = 0; n < 4; ++n)
#pragma unroll
            for (int r = 0; r < 4; ++r) accv[n][r] *= fr[r];

        // ---- Ps write: packed dwords, kh ^= qsw swizzle
#pragma unroll
        for (int n = 0; n < 4; ++n)
#pragma unroll
            for (int u = 0; u < 2; ++u) {
                unsigned kh = 2 * n + (lg >> 1);
                unsigned klo = 4 * (lg & 1) + 2 * u;
                unsigned col = (kh ^ qsw) * 8 + klo;
                unsigned pk = (unsigned)f2bf(pv[n][2 * u]) | ((unsigned)f2bf(pv[n][2 * u + 1]) << 16);
                *(unsigned*)&Ps[(w * 16 + i) * VP + col] = pk;
            }

        // ---- PV: mfma(A=Ps, B=VT) -> O[q][d]
#pragma unroll
        for (int ks = 0; ks < 2; ++ks) {
            short8v pf = *(const short8v*)&Ps[(w * 16 + i) * VP + ((ks * 4 + lg) ^ qsw) * 8];
#pragma unroll
            for (int n = 0; n < 4; ++n) {
                int d = n * 16 + i;
                short8v vf = *(const short8v*)&VT[d * VP + (((ks * 4 + lg) ^ ((d >> 3) & 7)) * 8)];
                accv[n] = __builtin_amdgcn_mfma_f32_16x16x32_bf16(pf, vf, accv[n], 0, 0, 0);
            }
        }
    }

    // ---- epilogue: normalize, write V2' [hi|lo] in buggy-reshape layout
    float linv = 1.f / l_run;
    float lr[4];
#pragma unroll
    for (int r = 0; r < 4; ++r) lr[r] = __shfl(linv, lg * 4 + r);
#pragma unroll
    for (int r = 0; r < 4; ++r) {
        int s_ = qb * 64 + w * 16 + lg * 4 + r;
        size_t row2 = (size_t)(b * 1024 + h * 64 + (s_ >> 4)) * 2048;
        int colh = (s_ & 15) * 64;
#pragma unroll
        for (int n = 0; n < 4; ++n) {
            int d = n * 16 + i;
            float val = accv[n][r] * lr[r];
            unsigned short hh2 = f2bf(val);
            V2p[row2 + colh + d] = hh2;
            V2p[row2 + 1024 + colh + d] = f2bf(val - bf2f(hh2));
        }
    }
}

// ---------------- GEMM2: out projection, M=8192 N=1024 K'=3072
__global__ __launch_bounds__(256) void gemm2_out(
    const unsigned short* __restrict__ V2,    // [8192][2048] = [hi|lo]
    const unsigned short* __restrict__ Wop,   // [1024][2048] = [h|l]
    const float* __restrict__ bias,           // [1024]
    float* __restrict__ Out)                  // [8192][1024]
{
    __shared__ unsigned short As[128 * 32];
    __shared__ unsigned short Bs[128 * 32];

    const int tid = threadIdx.x;
    const int lane = tid & 63, wave = tid >> 6;
    const int wr = wave >> 1, wc = wave & 1;
    // XCD swizzle: grid (8, 64) -> 512 = 8 * 64
    const int wg = blockIdx.y * 8 + blockIdx.x;
    const int swz = (wg & 7) * 64 + (wg >> 3);
    const int bm = (swz / 8) * 128, bn = (swz % 8) * 128;

    floatx4 acc[4][4] = {};

    for (int k0 = 0; k0 < 3072; k0 += 32) {
        const int region = k0 >> 10;
        const int acol = ((region == 2) ? 1024 : 0) + (k0 & 1023);
        const int bcol = ((region == 1) ? 1024 : 0) + (k0 & 1023);

        __syncthreads();

#pragma unroll
        for (int c = 0; c < 2; ++c) {
            int o = wave * 2048 + c * 1024 + lane * 16;
            int row = o >> 6, ce = (o & 63) >> 1;
            gload_lds16(V2 + (size_t)(bm + row) * 2048 + acol + ce, (char*)As + o);
            gload_lds16(Wop + (size_t)(bn + row) * 2048 + bcol + ce, (char*)Bs + o);
        }

        __syncthreads();

        short8v af[4], bf[4];
#pragma unroll
        for (int m = 0; m < 4; ++m)
            af[m] = *(short8v*)((char*)As + (wr * 64 + m * 16 + (lane & 15)) * 64 + (lane >> 4) * 16);
#pragma unroll
        for (int n = 0; n < 4; ++n)
            bf[n] = *(short8v*)((char*)Bs + (wc * 64 + n * 16 + (lane & 15)) * 64 + (lane >> 4) * 16);
#pragma unroll
        for (int m = 0; m < 4; ++m)
#pragma unroll
            for (int n = 0; n < 4; ++n)
                acc[m][n] = __builtin_amdgcn_mfma_f32_16x16x32_bf16(af[m], bf[n], acc[m][n], 0, 0, 0);
    }

#pragma unroll
    for (int n = 0; n < 4; ++n) {
        int col = bn + wc * 64 + n * 16 + (lane & 15);
        float bb = bias[col];
#pragma unroll
        for (int m = 0; m < 4; ++m)
#pragma unroll
            for (int j = 0; j < 4; ++j) {
                int row = bm + wr * 64 + m * 16 + (lane >> 4) * 4 + j;
                Out[(size_t)row * 1024 + col] = acc[m][n][j] + bb;
            }
    }
}

extern "C" void kernel_launch(void* const* d_in, const int* in_sizes, int n_in,
                              void* d_out, int out_size, void* d_ws, size_t ws_size,
                              hipStream_t stream)
{
    const float* x    = (const float*)d_in[0];
    const float* mask = (const float*)d_in[1];
    const float* Wqkv = (const float*)d_in[2];
    const float* bqkv = (const float*)d_in[3];
    const float* Wo   = (const float*)d_in[4];
    const float* bo   = (const float*)d_in[5];
    float* out = (float*)d_out;

    // workspace layout, peak 124 MiB (<=128 MiB proven in round 1):
    //   [0,32M)    Xp  [8192][2048]  -> later V2p (Xp dead after gemm1)
    //   [32,80M)   qkv_hi [8192][3072]
    //   [80,112M)  qk_lo [8192][2048]
    //   [112,124M) Wp [3072][2048]   -> later Wop [1024][2048] (Wp dead after gemm1)
    char* w = (char*)d_ws;
    unsigned short* Xp     = (unsigned short*)w;
    unsigned short* V2p    = (unsigned short*)w;
    unsigned short* qkv_hi = (unsigned short*)(w + 33554432);
    unsigned short* qk_lo  = (unsigned short*)(w + 83886080);
    unsigned short* Wp     = (unsigned short*)(w + 117440512);
    unsigned short* Wop    = (unsigned short*)(w + 117440512);

    conv_split<<<8192, 256, 0, stream>>>(x, Xp);        // X -> [Xh|Xl]
    conv_split<<<3072, 256, 0, stream>>>(Wqkv, Wp);     // Wqkv -> [h|l]

    gemm1_qkv<<<dim3(24, 64), 256, 0, stream>>>(Xp, Wp, bqkv, qkv_hi, qk_lo);

    conv_split<<<1024, 256, 0, stream>>>(Wo, Wop);      // after gemm1 (aliases Wp)

    attn_mfma2<<<dim3(16, 16, 8), 256, 0, stream>>>(qkv_hi, qk_lo, mask, V2p);

    gemm2_out<<<dim3(8, 64), 256, 0, stream>>>(V2p, Wop, bo, out);
}

// Round 8
// 523.220 us; speedup vs baseline: 4.4434x; 1.0139x over previous
//
#include <hip/hip_runtime.h>
#include <math.h>

// B=8, S=1024, D=1024, H=16, HD=64.  M = B*S = 8192 tokens.
// Split-bf16 (hi+lo) MFMA everywhere: C = Ah*Bh + Ah*Bl + Al*Bh via K'=3072
// with piecewise region maps over [h|l]-paired operands.
// gemm1: qkv = x @ Wqkv^T + b; epilogue stores qkv_hi (q pre-scaled 0.125) + qk_lo.
// attn : swapped-QK MFMA flash attention (Q hoisted to regs), swizzled LDS,
//        mask pre-transposed + register-prefetched, defer-max, setprio.
// gemm2: out = V2 @ Wo^T + bo.

typedef __attribute__((ext_vector_type(8))) short short8v;
typedef __attribute__((ext_vector_type(4))) float floatx4;

__device__ inline unsigned short f2bf(float f) {
    return __builtin_bit_cast(unsigned short, (__bf16)f);
}
__device__ inline float bf2f(unsigned short u) {
    return (float)__builtin_bit_cast(__bf16, u);
}

__device__ inline void gload_lds16(const void* g, void* l) {
    __builtin_amdgcn_global_load_lds((const __attribute__((address_space(1))) void*)g,
                                     (__attribute__((address_space(3))) void*)l,
                                     16, 0, 0);
}

// ---------------- split fp32 [N][1024] -> bf16 [N][2048] = [hi|lo]
__global__ __launch_bounds__(256) void conv_split(
    const float* __restrict__ W, unsigned short* __restrict__ Wp)
{
    int i = (blockIdx.x * 256 + threadIdx.x) * 4;
    int row = i >> 10, c = i & 1023;
    float4 v = *(const float4*)&W[i];
    float f[4] = {v.x, v.y, v.z, v.w};
    unsigned short hs[4], ls[4];
#pragma unroll
    for (int j = 0; j < 4; ++j) {
        hs[j] = f2bf(f[j]);
        ls[j] = f2bf(f[j] - bf2f(hs[j]));
    }
    ushort4 h4 = {hs[0], hs[1], hs[2], hs[3]};
    ushort4 l4 = {ls[0], ls[1], ls[2], ls[3]};
    size_t base = (size_t)row * 2048;
    *(ushort4*)&Wp[base + c] = h4;
    *(ushort4*)&Wp[base + 1024 + c] = l4;
}

// ---------------- mask [1024][1024] -> maskT [1024][1024] (transpose)
__global__ __launch_bounds__(256) void transpose_mask(
    const float* __restrict__ m, float* __restrict__ mt)
{
    __shared__ float t[64][65];
    const int bx = blockIdx.x * 64, by = blockIdx.y * 64;
    const int tx = threadIdx.x & 63, r0 = (threadIdx.x >> 6) * 16;
#pragma unroll
    for (int r = 0; r < 16; ++r)
        t[r0 + r][tx] = m[(size_t)(by + r0 + r) * 1024 + bx + tx];
    __syncthreads();
#pragma unroll
    for (int r = 0; r < 16; ++r)
        mt[(size_t)(bx + r0 + r) * 1024 + by + tx] = t[tx][r0 + r];
}

// ---------------- GEMM1: qkv projection, M=8192 N=3072 K'=3072
__global__ __launch_bounds__(256) void gemm1_qkv(
    const unsigned short* __restrict__ Xp,    // [8192][2048] = [Xh|Xl]
    const unsigned short* __restrict__ Wp,    // [3072][2048] = [Wh|Wl]
    const float* __restrict__ bias,           // [3072]
    unsigned short* __restrict__ qkv_hi,      // [8192][3072]; q cols pre-scaled 0.125
    unsigned short* __restrict__ qk_lo)       // [8192][2048] per head: q_lo(64)|k_lo(64)
{
    __shared__ unsigned short As[128 * 32];   // 8KB [128][32]
    __shared__ unsigned short Bs[128 * 32];

    const int tid = threadIdx.x;
    const int lane = tid & 63, wave = tid >> 6;
    const int wr = wave >> 1, wc = wave & 1;
    // XCD-aware swizzle: grid (24, 64) -> 1536 = 8 * 192
    const int wg = blockIdx.y * 24 + blockIdx.x;
    const int swz = (wg & 7) * 192 + (wg >> 3);
    const int bm = (swz / 24) * 128, bn = (swz % 24) * 128;

    floatx4 acc[4][4] = {};

    for (int k0 = 0; k0 < 3072; k0 += 32) {
        const int region = k0 >> 10;
        const int acol = ((region == 2) ? 1024 : 0) + (k0 & 1023);
        const int bcol = ((region == 1) ? 1024 : 0) + (k0 & 1023);

        __syncthreads();

#pragma unroll
        for (int c = 0; c < 2; ++c) {
            int o = wave * 2048 + c * 1024 + lane * 16;   // byte offset in tile
            int row = o >> 6, ce = (o & 63) >> 1;         // ce: elem offset 0..31
            gload_lds16(Xp + (size_t)(bm + row) * 2048 + acol + ce, (char*)As + o);
            gload_lds16(Wp + (size_t)(bn + row) * 2048 + bcol + ce, (char*)Bs + o);
        }

        __syncthreads();

        short8v af[4], bf[4];
#pragma unroll
        for (int m = 0; m < 4; ++m)
            af[m] = *(short8v*)((char*)As + (wr * 64 + m * 16 + (lane & 15)) * 64 + (lane >> 4) * 16);
#pragma unroll
        for (int n = 0; n < 4; ++n)
            bf[n] = *(short8v*)((char*)Bs + (wc * 64 + n * 16 + (lane & 15)) * 64 + (lane >> 4) * 16);
#pragma unroll
        for (int m = 0; m < 4; ++m)
#pragma unroll
            for (int n = 0; n < 4; ++n)
                acc[m][n] = __builtin_amdgcn_mfma_f32_16x16x32_bf16(af[m], bf[n], acc[m][n], 0, 0, 0);
    }

    // Epilogue: C/D layout col=lane&15, row=(lane>>4)*4+j.  q cols scaled 0.125.
#pragma unroll
    for (int n = 0; n < 4; ++n) {
        int col = bn + wc * 64 + n * 16 + (lane & 15);
        float bb = bias[col];
        int hh = col / 192, within = col % 192;
#pragma unroll
        for (int m = 0; m < 4; ++m)
#pragma unroll
            for (int j = 0; j < 4; ++j) {
                int row = bm + wr * 64 + m * 16 + (lane >> 4) * 4 + j;
                float val = acc[m][n][j] + bb;
                if (within < 64) {                // q: pre-scale by 1/sqrt(64)
                    float vs = val * 0.125f;
                    unsigned short h = f2bf(vs);
                    qkv_hi[(size_t)row * 3072 + col] = h;
                    qk_lo[(size_t)row * 2048 + hh * 128 + within] = f2bf(vs - bf2f(h));
                } else if (within < 128) {        // k
                    unsigned short h = f2bf(val);
                    qkv_hi[(size_t)row * 3072 + col] = h;
                    qk_lo[(size_t)row * 2048 + hh * 128 + within] = f2bf(val - bf2f(h));
                } else {                          // v
                    qkv_hi[(size_t)row * 3072 + col] = f2bf(val);
                }
            }
    }
}

// ---------------- attention v3: swapped-QK MFMA flash, grid (16, 16, 8)
#define QP 200   // Ks row stride (elems)
#define VP 72    // VT / Ps row stride (elems)

__global__ __launch_bounds__(256) void attn_mfma3(
    const unsigned short* __restrict__ qkv_hi,  // [8192][3072] (q scaled)
    const unsigned short* __restrict__ qk_lo,   // [8192][2048] (q_lo scaled)
    const float* __restrict__ maskT,            // [1024][1024] transposed mask
    unsigned short* __restrict__ V2p)           // [8192][2048] = [hi|lo]
{
    __shared__ unsigned short Ks[64 * QP];   // 25.6KB [Kh|Kl|Kh]
    __shared__ unsigned short VT[64 * VP];   // 9.2KB  V^T swizzled
    __shared__ unsigned short Ps[64 * VP];   // 9.2KB  P swizzled
    // total 44KB -> 3 blocks/CU

    const int tid = threadIdx.x, lane = tid & 63, w = tid >> 6;
    const int i = lane & 15, lg = lane >> 4;
    const int qb = blockIdx.x, h = blockIdx.y, b = blockIdx.z;
    const size_t hi_base = (size_t)b * 1024 * 3072;
    const size_t lo_base = (size_t)b * 1024 * 2048;
    const int hk = h * 192 + 64, hv = h * 192 + 128;
    const int lq = h * 128, lk = h * 128 + 64;
    const int hq = h * 192;

    // ---- hoist Q' into registers (B-frag layout). cols: [Qh|Qh|Ql], all scaled.
    short8v qf[6];
    {
        const int qrow = qb * 64 + w * 16 + i;
#pragma unroll
        for (int ks = 0; ks < 6; ++ks) {
            int c = ks * 32 + lg * 8;
            const unsigned short* src = (c < 128)
                ? qkv_hi + hi_base + (size_t)qrow * 3072 + hq + (c & 63)
                : qk_lo + lo_base + (size_t)qrow * 2048 + lq + (c - 128);
            qf[ks] = *(const short8v*)src;
        }
    }

    // staging registers
    short8v kreg[6], vreg[2];
    float mreg[16];
    const int kr = tid >> 2, d0 = (tid & 3) * 16;   // V staging coords

    auto load_kv = [&](int ch) {
#pragma unroll
        for (int p = 0; p < 6; ++p) {
            int c = p * 256 + tid;
            int r = c / 24, k8 = (c % 24) * 8;
            const unsigned short* s;
            if (k8 < 64)       s = qkv_hi + hi_base + (size_t)(ch * 64 + r) * 3072 + hk + k8;
            else if (k8 < 128) s = qk_lo + lo_base + (size_t)(ch * 64 + r) * 2048 + lk + (k8 - 64);
            else               s = qkv_hi + hi_base + (size_t)(ch * 64 + r) * 3072 + hk + (k8 - 128);
            kreg[p] = *(const short8v*)s;
        }
        const unsigned short* vsrc = qkv_hi + hi_base + (size_t)(ch * 64 + kr) * 3072 + hv + d0;
        vreg[0] = *(const short8v*)vsrc;
        vreg[1] = *(const short8v*)(vsrc + 8);
    };

    // mask prefetch: lane's own 16 values from maskT[k][q] (coalesced in q)
    auto load_mask = [&](int ch) {
#pragma unroll
        for (int n = 0; n < 4; ++n)
#pragma unroll
            for (int r = 0; r < 4; ++r)
                mreg[n * 4 + r] = maskT[(size_t)(ch * 64 + n * 16 + lg * 4 + r) * 1024
                                        + qb * 64 + w * 16 + i];
    };

    auto write_ch = [&]() {
#pragma unroll
        for (int p = 0; p < 6; ++p) {
            int c = p * 256 + tid;
            int r = c / 24, k8 = (c % 24) * 8;
            *(short8v*)&Ks[r * QP + k8] = kreg[p];
        }
        // V^T with kh ^= (d>>3)&7 swizzle (2-way banks both sides)
        {
            unsigned kh = kr >> 3, klo = kr & 7;
#pragma unroll
            for (int j = 0; j < 16; ++j) {
                unsigned short vv = (j < 8) ? (unsigned short)vreg[0][j] : (unsigned short)vreg[1][j - 8];
                int d = d0 + j;
                VT[d * VP + ((kh ^ ((d >> 3) & 7)) * 8 + klo)] = vv;
            }
        }
    };

    load_kv(0);
    load_mask(0);
    float m_run = -3e30f, l_run = 0.f;
    floatx4 accv[4] = {};
    const unsigned qsw = ((w * 16 + i) >> 2) & 7;   // Ps swizzle key (own q)

    for (int ch = 0; ch < 16; ++ch) {
        __syncthreads();       // previous compute done reading Ks/VT
        write_ch();
        __syncthreads();       // staging visible
        if (ch < 15) load_kv(ch + 1);   // prefetch next K/V under compute (T14)

        // ---- scores S^T[k][q]: mfma(A=K from LDS, B=Q from regs)
        floatx4 sc[4] = {};
        __builtin_amdgcn_s_setprio(1);
#pragma unroll
        for (int ks = 0; ks < 6; ++ks) {
#pragma unroll
            for (int n = 0; n < 4; ++n) {
                short8v kf = *(const short8v*)&Ks[(n * 16 + i) * QP + ks * 32 + lg * 8];
                sc[n] = __builtin_amdgcn_mfma_f32_16x16x32_bf16(kf, qf[ks], sc[n], 0, 0, 0);
            }
        }
        __builtin_amdgcn_s_setprio(0);

        // ---- mask add + lane-local softmax (lane owns q = w*16+i; k = n*16+lg*4+r)
        float sv[4][4];
        float cmax = -3e30f;
#pragma unroll
        for (int n = 0; n < 4; ++n)
#pragma unroll
            for (int r = 0; r < 4; ++r) {
                float val = sc[n][r] + mreg[n * 4 + r];
                sv[n][r] = val;
                cmax = fmaxf(cmax, val);
            }
        cmax = fmaxf(cmax, __shfl_xor(cmax, 16));
        cmax = fmaxf(cmax, __shfl_xor(cmax, 32));

        // defer-max (T13): rescale only if some row's max grew by > 8
        if (!__all(cmax - m_run <= 8.f)) {
            float mnew = fmaxf(m_run, cmax);
            float fct = __expf(m_run - mnew);
            m_run = mnew;
            l_run *= fct;
            float fr[4];
#pragma unroll
            for (int r = 0; r < 4; ++r) fr[r] = __shfl(fct, lg * 4 + r);
#pragma unroll
            for (int n = 0; n < 4; ++n)
#pragma unroll
                for (int r = 0; r < 4; ++r) accv[n][r] *= fr[r];
        }

        float rsum = 0.f;
        float pv[4][4];
#pragma unroll
        for (int n = 0; n < 4; ++n)
#pragma unroll
            for (int r = 0; r < 4; ++r) {
                float pp = __expf(sv[n][r] - m_run);   // bounded by e^8
                pv[n][r] = pp;
                rsum += pp;
            }
        rsum += __shfl_xor(rsum, 16);
        rsum += __shfl_xor(rsum, 32);
        l_run += rsum;

        if (ch < 15) load_mask(ch + 1);   // prefetch next mask after current use

        // ---- Ps write: packed dwords, kh ^= qsw swizzle
#pragma unroll
        for (int n = 0; n < 4; ++n)
#pragma unroll
            for (int u = 0; u < 2; ++u) {
                unsigned kh = 2 * n + (lg >> 1);
                unsigned klo = 4 * (lg & 1) + 2 * u;
                unsigned col = (kh ^ qsw) * 8 + klo;
                unsigned pk = (unsigned)f2bf(pv[n][2 * u]) | ((unsigned)f2bf(pv[n][2 * u + 1]) << 16);
                *(unsigned*)&Ps[(w * 16 + i) * VP + col] = pk;
            }

        // ---- PV: mfma(A=Ps, B=VT) -> O[q][d]
        __builtin_amdgcn_s_setprio(1);
#pragma unroll
        for (int ks = 0; ks < 2; ++ks) {
            short8v pf = *(const short8v*)&Ps[(w * 16 + i) * VP + ((ks * 4 + lg) ^ qsw) * 8];
#pragma unroll
            for (int n = 0; n < 4; ++n) {
                int d = n * 16 + i;
                short8v vf = *(const short8v*)&VT[d * VP + (((ks * 4 + lg) ^ ((d >> 3) & 7)) * 8)];
                accv[n] = __builtin_amdgcn_mfma_f32_16x16x32_bf16(pf, vf, accv[n], 0, 0, 0);
            }
        }
        __builtin_amdgcn_s_setprio(0);
    }

    // ---- epilogue: normalize, write V2' [hi|lo] in buggy-reshape layout
    float linv = 1.f / l_run;
    float lr[4];
#pragma unroll
    for (int r = 0; r < 4; ++r) lr[r] = __shfl(linv, lg * 4 + r);
#pragma unroll
    for (int r = 0; r < 4; ++r) {
        int s_ = qb * 64 + w * 16 + lg * 4 + r;
        size_t row2 = (size_t)(b * 1024 + h * 64 + (s_ >> 4)) * 2048;
        int colh = (s_ & 15) * 64;
#pragma unroll
        for (int n = 0; n < 4; ++n) {
            int d = n * 16 + i;
            float val = accv[n][r] * lr[r];
            unsigned short hh2 = f2bf(val);
            V2p[row2 + colh + d] = hh2;
            V2p[row2 + 1024 + colh + d] = f2bf(val - bf2f(hh2));
        }
    }
}

// ---------------- GEMM2: out projection, M=8192 N=1024 K'=3072
__global__ __launch_bounds__(256) void gemm2_out(
    const unsigned short* __restrict__ V2,    // [8192][2048] = [hi|lo]
    const unsigned short* __restrict__ Wop,   // [1024][2048] = [h|l]
    const float* __restrict__ bias,           // [1024]
    float* __restrict__ Out)                  // [8192][1024]
{
    __shared__ unsigned short As[128 * 32];
    __shared__ unsigned short Bs[128 * 32];

    const int tid = threadIdx.x;
    const int lane = tid & 63, wave = tid >> 6;
    const int wr = wave >> 1, wc = wave & 1;
    // XCD swizzle: grid (8, 64) -> 512 = 8 * 64
    const int wg = blockIdx.y * 8 + blockIdx.x;
    const int swz = (wg & 7) * 64 + (wg >> 3);
    const int bm = (swz / 8) * 128, bn = (swz % 8) * 128;

    floatx4 acc[4][4] = {};

    for (int k0 = 0; k0 < 3072; k0 += 32) {
        const int region = k0 >> 10;
        const int acol = ((region == 2) ? 1024 : 0) + (k0 & 1023);
        const int bcol = ((region == 1) ? 1024 : 0) + (k0 & 1023);

        __syncthreads();

#pragma unroll
        for (int c = 0; c < 2; ++c) {
            int o = wave * 2048 + c * 1024 + lane * 16;
            int row = o >> 6, ce = (o & 63) >> 1;
            gload_lds16(V2 + (size_t)(bm + row) * 2048 + acol + ce, (char*)As + o);
            gload_lds16(Wop + (size_t)(bn + row) * 2048 + bcol + ce, (char*)Bs + o);
        }

        __syncthreads();

        short8v af[4], bf[4];
#pragma unroll
        for (int m = 0; m < 4; ++m)
            af[m] = *(short8v*)((char*)As + (wr * 64 + m * 16 + (lane & 15)) * 64 + (lane >> 4) * 16);
#pragma unroll
        for (int n = 0; n < 4; ++n)
            bf[n] = *(short8v*)((char*)Bs + (wc * 64 + n * 16 + (lane & 15)) * 64 + (lane >> 4) * 16);
#pragma unroll
        for (int m = 0; m < 4; ++m)
#pragma unroll
            for (int n = 0; n < 4; ++n)
                acc[m][n] = __builtin_amdgcn_mfma_f32_16x16x32_bf16(af[m], bf[n], acc[m][n], 0, 0, 0);
    }

#pragma unroll
    for (int n = 0; n < 4; ++n) {
        int col = bn + wc * 64 + n * 16 + (lane & 15);
        float bb = bias[col];
#pragma unroll
        for (int m = 0; m < 4; ++m)
#pragma unroll
            for (int j = 0; j < 4; ++j) {
                int row = bm + wr * 64 + m * 16 + (lane >> 4) * 4 + j;
                Out[(size_t)row * 1024 + col] = acc[m][n][j] + bb;
            }
    }
}

extern "C" void kernel_launch(void* const* d_in, const int* in_sizes, int n_in,
                              void* d_out, int out_size, void* d_ws, size_t ws_size,
                              hipStream_t stream)
{
    const float* x    = (const float*)d_in[0];
    const float* mask = (const float*)d_in[1];
    const float* Wqkv = (const float*)d_in[2];
    const float* bqkv = (const float*)d_in[3];
    const float* Wo   = (const float*)d_in[4];
    const float* bo   = (const float*)d_in[5];
    float* out = (float*)d_out;

    // workspace layout, peak 124 MiB:
    //   [0,32M)     Xp [8192][2048]   -> later V2p (Xp dead after gemm1)
    //   [32,80M)    qkv_hi [8192][3072]
    //   [80,112M)   qk_lo [8192][2048]
    //   [112,124M)  Wp [3072][2048]   -> later Wop [1024][2048] (@112M) +
    //                                    maskT [1024][1024] f32 (@116M)
    char* w = (char*)d_ws;
    unsigned short* Xp     = (unsigned short*)w;
    unsigned short* V2p    = (unsigned short*)w;
    unsigned short* qkv_hi = (unsigned short*)(w + 33554432);
    unsigned short* qk_lo  = (unsigned short*)(w + 83886080);
    unsigned short* Wp     = (unsigned short*)(w + 117440512);
    unsigned short* Wop    = (unsigned short*)(w + 117440512);
    float*          maskT  = (float*)(w + 117440512 + 4194304);

    conv_split<<<8192, 256, 0, stream>>>(x, Xp);        // X -> [Xh|Xl]
    conv_split<<<3072, 256, 0, stream>>>(Wqkv, Wp);     // Wqkv -> [h|l]

    gemm1_qkv<<<dim3(24, 64), 256, 0, stream>>>(Xp, Wp, bqkv, qkv_hi, qk_lo);

    conv_split<<<1024, 256, 0, stream>>>(Wo, Wop);      // after gemm1 (aliases Wp)
    transpose_mask<<<dim3(16, 16), 256, 0, stream>>>(mask, maskT);  // aliases dead Wp tail

    attn_mfma3<<<dim3(16, 16, 8), 256, 0, stream>>>(qkv_hi, qk_lo, maskT, V2p);

    gemm2_out<<<dim3(8, 64), 256, 0, stream>>>(V2p, Wop, bo, out);
}

// Round 9
// 477.847 us; speedup vs baseline: 4.8653x; 1.0950x over previous
//
#include <hip/hip_runtime.h>
#include <math.h>

// B=8, S=1024, D=1024, H=16, HD=64.  M = B*S = 8192 tokens.
// Split-bf16 (hi+lo) MFMA everywhere: C = Ah*Bh + Ah*Bl + Al*Bh via K'=3072.
// gemm1/gemm2: 256x128-tile, BK=64, ring-3 LDS, counted-vmcnt pipeline
//   (raw s_barrier + vmcnt(6), XOR-swizzled LDS, setprio around MFMA).
// attn: swapped-QK MFMA flash (unchanged from round 8, passing).

typedef __attribute__((ext_vector_type(8))) short short8v;
typedef __attribute__((ext_vector_type(4))) float floatx4;

__device__ inline unsigned short f2bf(float f) {
    return __builtin_bit_cast(unsigned short, (__bf16)f);
}
__device__ inline float bf2f(unsigned short u) {
    return (float)__builtin_bit_cast(__bf16, u);
}

__device__ inline void gload_lds16(const void* g, void* l) {
    __builtin_amdgcn_global_load_lds((const __attribute__((address_space(1))) void*)g,
                                     (__attribute__((address_space(3))) void*)l,
                                     16, 0, 0);
}

// ---------------- split fp32 [N][1024] -> bf16 [N][2048] = [hi|lo]
__global__ __launch_bounds__(256) void conv_split(
    const float* __restrict__ W, unsigned short* __restrict__ Wp)
{
    int i = (blockIdx.x * 256 + threadIdx.x) * 4;
    int row = i >> 10, c = i & 1023;
    float4 v = *(const float4*)&W[i];
    float f[4] = {v.x, v.y, v.z, v.w};
    unsigned short hs[4], ls[4];
#pragma unroll
    for (int j = 0; j < 4; ++j) {
        hs[j] = f2bf(f[j]);
        ls[j] = f2bf(f[j] - bf2f(hs[j]));
    }
    ushort4 h4 = {hs[0], hs[1], hs[2], hs[3]};
    ushort4 l4 = {ls[0], ls[1], ls[2], ls[3]};
    size_t base = (size_t)row * 2048;
    *(ushort4*)&Wp[base + c] = h4;
    *(ushort4*)&Wp[base + 1024 + c] = l4;
}

// ---------------- mask [1024][1024] -> maskT (transpose)
__global__ __launch_bounds__(256) void transpose_mask(
    const float* __restrict__ m, float* __restrict__ mt)
{
    __shared__ float t[64][65];
    const int bx = blockIdx.x * 64, by = blockIdx.y * 64;
    const int tx = threadIdx.x & 63, r0 = (threadIdx.x >> 6) * 16;
#pragma unroll
    for (int r = 0; r < 16; ++r)
        t[r0 + r][tx] = m[(size_t)(by + r0 + r) * 1024 + bx + tx];
    __syncthreads();
#pragma unroll
    for (int r = 0; r < 16; ++r)
        mt[(size_t)(bx + r0 + r) * 1024 + by + tx] = t[tx][r0 + r];
}

// ============ pipelined GEMM core (shared by gemm1/gemm2) ============
// Tile 256(M) x 128(N), BK=64, 48 K-tiles, 512 threads = 8 waves (4M x 2N),
// per-wave 64x64 output (acc[4][4]).  LDS ring of 3 slots (48KB each):
//   slot s: A [256][64] at s*49152, B [128][64] at s*49152+32768, bf16,
//   XOR swizzle: 16B-slot index sc stores logical col16 = sc ^ (row&7).
// Staging: global_load_lds with pre-swizzled per-lane source (rule #21).
// Per K-tile: 2 phases { 3 gload_lds ; 12 ds_read_b128 ; 16 MFMA w/ setprio },
// then vmcnt(6) [drain at t>=46] + raw s_barrier (loads span barriers, T4).

#define GSTAGE_A(SRC, t, st, c) { \
    int row_ = (c) * 64 + srow; \
    int gcol_ = ((sc ^ (row_ & 7)) << 3); \
    int acol_ = (((t) >= 32) ? 1024 : 0) + (((t) << 6) & 1023); \
    gload_lds16(SRC + (size_t)(bm + row_) * 2048 + acol_ + gcol_, \
                (char*)lds + (st) * 49152 + (c) * 8192 + tid * 16); }
#define GSTAGE_B(SRC, t, st, c) { \
    int row_ = (c) * 64 + srow; \
    int gcol_ = ((sc ^ (row_ & 7)) << 3); \
    int bcol_ = ((((t) >= 16) && ((t) < 32)) ? 1024 : 0) + (((t) << 6) & 1023); \
    gload_lds16(SRC + (size_t)(bn + row_) * 2048 + bcol_ + gcol_, \
                (char*)lds + (st) * 49152 + 32768 + (c) * 8192 + tid * 16); }

#define GEMM_PIPELINE_BODY(ASRC, BSRC) \
    floatx4 acc[4][4] = {}; \
    const int srow = tid >> 3, sc = tid & 7; \
    GSTAGE_A(ASRC, 0, 0, 0) GSTAGE_A(ASRC, 0, 0, 1) GSTAGE_A(ASRC, 0, 0, 2) GSTAGE_A(ASRC, 0, 0, 3) \
    GSTAGE_B(BSRC, 0, 0, 0) GSTAGE_B(BSRC, 0, 0, 1) \
    GSTAGE_A(ASRC, 1, 1, 0) GSTAGE_A(ASRC, 1, 1, 1) GSTAGE_A(ASRC, 1, 1, 2) GSTAGE_A(ASRC, 1, 1, 3) \
    GSTAGE_B(BSRC, 1, 1, 0) GSTAGE_B(BSRC, 1, 1, 1) \
    asm volatile("s_waitcnt vmcnt(6)"); \
    __builtin_amdgcn_sched_barrier(0); \
    __builtin_amdgcn_s_barrier(); \
    __builtin_amdgcn_sched_barrier(0); \
    int cs = 0, ns = 2; \
    _Pragma("unroll 1") \
    for (int t = 0; t < 48; ++t) { \
        const char* sA = (const char*)lds + cs * 49152; \
        const char* sB = sA + 32768; \
        const bool do_stage = (t + 2 < 48); \
        _Pragma("unroll") \
        for (int p = 0; p < 2; ++p) { \
            if (do_stage) { \
                if (p == 0) { GSTAGE_A(ASRC, t + 2, ns, 0) GSTAGE_A(ASRC, t + 2, ns, 1) GSTAGE_B(BSRC, t + 2, ns, 0) } \
                else        { GSTAGE_A(ASRC, t + 2, ns, 2) GSTAGE_A(ASRC, t + 2, ns, 3) GSTAGE_B(BSRC, t + 2, ns, 1) } \
            } \
            short8v af[2][2], bf[4][2]; \
            _Pragma("unroll") \
            for (int mm = 0; mm < 2; ++mm) \
                _Pragma("unroll") \
                for (int k = 0; k < 2; ++k) { \
                    int r = wr * 64 + (p * 2 + mm) * 16 + i; \
                    int c16 = k * 4 + lg; \
                    af[mm][k] = *(const short8v*)(sA + r * 128 + ((c16 ^ (r & 7)) << 4)); \
                } \
            _Pragma("unroll") \
            for (int n = 0; n < 4; ++n) \
                _Pragma("unroll") \
                for (int k = 0; k < 2; ++k) { \
                    int r = wc * 64 + n * 16 + i; \
                    int c16 = k * 4 + lg; \
                    bf[n][k] = *(const short8v*)(sB + r * 128 + ((c16 ^ (r & 7)) << 4)); \
                } \
            __builtin_amdgcn_s_setprio(1); \
            _Pragma("unroll") \
            for (int mm = 0; mm < 2; ++mm) \
                _Pragma("unroll") \
                for (int n = 0; n < 4; ++n) \
                    _Pragma("unroll") \
                    for (int k = 0; k < 2; ++k) \
                        acc[p * 2 + mm][n] = __builtin_amdgcn_mfma_f32_16x16x32_bf16( \
                            af[mm][k], bf[n][k], acc[p * 2 + mm][n], 0, 0, 0); \
            __builtin_amdgcn_s_setprio(0); \
        } \
        if (t >= 46) { asm volatile("s_waitcnt vmcnt(0)"); } \
        else         { asm volatile("s_waitcnt vmcnt(6)"); } \
        __builtin_amdgcn_sched_barrier(0); \
        __builtin_amdgcn_s_barrier(); \
        __builtin_amdgcn_sched_barrier(0); \
        cs = (cs == 2) ? 0 : cs + 1; \
        ns = (ns == 2) ? 0 : ns + 1; \
    }

// ---------------- GEMM1: qkv projection, M=8192 N=3072 K'=3072
__global__ __launch_bounds__(512) void gemm1_qkv8(
    const unsigned short* __restrict__ Xp,    // [8192][2048] = [Xh|Xl]
    const unsigned short* __restrict__ Wp,    // [3072][2048] = [Wh|Wl]
    const float* __restrict__ bias,           // [3072]
    unsigned short* __restrict__ qkv_hi,      // [8192][3072]; q cols pre-scaled 0.125
    unsigned short* __restrict__ qk_lo)       // [8192][2048] per head: q_lo|k_lo
{
    __shared__ unsigned short lds[3 * 24576];   // 144KB
    const int tid = threadIdx.x;
    const int lane = tid & 63, w = tid >> 6;
    const int wr = w >> 1, wc = w & 1;
    const int i = lane & 15, lg = lane >> 4;
    // XCD swizzle: grid (24, 32) -> 768 = 8 * 96
    const int wg = blockIdx.y * 24 + blockIdx.x;
    const int swz = (wg & 7) * 96 + (wg >> 3);
    const int bm = (swz / 24) * 256, bn = (swz % 24) * 128;

    GEMM_PIPELINE_BODY(Xp, Wp)

    // epilogue: C/D layout col=lane&15, row=(lane>>4)*4+j.  q cols scaled 0.125.
#pragma unroll
    for (int n = 0; n < 4; ++n) {
        int col = bn + wc * 64 + n * 16 + i;
        float bb = bias[col];
        int hh = col / 192, within = col % 192;
#pragma unroll
        for (int m = 0; m < 4; ++m)
#pragma unroll
            for (int j = 0; j < 4; ++j) {
                int row = bm + wr * 64 + m * 16 + lg * 4 + j;
                float val = acc[m][n][j] + bb;
                if (within < 64) {                // q: pre-scale by 1/sqrt(64)
                    float vs = val * 0.125f;
                    unsigned short h = f2bf(vs);
                    qkv_hi[(size_t)row * 3072 + col] = h;
                    qk_lo[(size_t)row * 2048 + hh * 128 + within] = f2bf(vs - bf2f(h));
                } else if (within < 128) {        // k
                    unsigned short h = f2bf(val);
                    qkv_hi[(size_t)row * 3072 + col] = h;
                    qk_lo[(size_t)row * 2048 + hh * 128 + within] = f2bf(val - bf2f(h));
                } else {                          // v
                    qkv_hi[(size_t)row * 3072 + col] = f2bf(val);
                }
            }
    }
}

// ---------------- GEMM2: out projection, M=8192 N=1024 K'=3072
__global__ __launch_bounds__(512) void gemm2_out8(
    const unsigned short* __restrict__ V2,    // [8192][2048] = [hi|lo]
    const unsigned short* __restrict__ Wop,   // [1024][2048] = [h|l]
    const float* __restrict__ bias,           // [1024]
    float* __restrict__ Out)                  // [8192][1024]
{
    __shared__ unsigned short lds[3 * 24576];
    const int tid = threadIdx.x;
    const int lane = tid & 63, w = tid >> 6;
    const int wr = w >> 1, wc = w & 1;
    const int i = lane & 15, lg = lane >> 4;
    // XCD swizzle: grid (8, 32) -> 256 = 8 * 32
    const int wg = blockIdx.y * 8 + blockIdx.x;
    const int swz = (wg & 7) * 32 + (wg >> 3);
    const int bm = (swz / 8) * 256, bn = (swz % 8) * 128;

    GEMM_PIPELINE_BODY(V2, Wop)

#pragma unroll
    for (int n = 0; n < 4; ++n) {
        int col = bn + wc * 64 + n * 16 + i;
        float bb = bias[col];
#pragma unroll
        for (int m = 0; m < 4; ++m)
#pragma unroll
            for (int j = 0; j < 4; ++j) {
                int row = bm + wr * 64 + m * 16 + lg * 4 + j;
                Out[(size_t)row * 1024 + col] = acc[m][n][j] + bb;
            }
    }
}

// ---------------- attention v3 (unchanged, passing): grid (16, 16, 8)
#define QP 200   // Ks row stride (elems)
#define VP 72    // VT / Ps row stride (elems)

__global__ __launch_bounds__(256) void attn_mfma3(
    const unsigned short* __restrict__ qkv_hi,  // [8192][3072] (q scaled)
    const unsigned short* __restrict__ qk_lo,   // [8192][2048] (q_lo scaled)
    const float* __restrict__ maskT,            // [1024][1024] transposed mask
    unsigned short* __restrict__ V2p)           // [8192][2048] = [hi|lo]
{
    __shared__ unsigned short Ks[64 * QP];
    __shared__ unsigned short VT[64 * VP];
    __shared__ unsigned short Ps[64 * VP];

    const int tid = threadIdx.x, lane = tid & 63, w = tid >> 6;
    const int i = lane & 15, lg = lane >> 4;
    const int qb = blockIdx.x, h = blockIdx.y, b = blockIdx.z;
    const size_t hi_base = (size_t)b * 1024 * 3072;
    const size_t lo_base = (size_t)b * 1024 * 2048;
    const int hk = h * 192 + 64, hv = h * 192 + 128;
    const int lq = h * 128, lk = h * 128 + 64;
    const int hq = h * 192;

    short8v qf[6];
    {
        const int qrow = qb * 64 + w * 16 + i;
#pragma unroll
        for (int ks = 0; ks < 6; ++ks) {
            int c = ks * 32 + lg * 8;
            const unsigned short* src = (c < 128)
                ? qkv_hi + hi_base + (size_t)qrow * 3072 + hq + (c & 63)
                : qk_lo + lo_base + (size_t)qrow * 2048 + lq + (c - 128);
            qf[ks] = *(const short8v*)src;
        }
    }

    short8v kreg[6], vreg[2];
    float mreg[16];
    const int kr = tid >> 2, d0 = (tid & 3) * 16;

    auto load_kv = [&](int ch) {
#pragma unroll
        for (int p = 0; p < 6; ++p) {
            int c = p * 256 + tid;
            int r = c / 24, k8 = (c % 24) * 8;
            const unsigned short* s;
            if (k8 < 64)       s = qkv_hi + hi_base + (size_t)(ch * 64 + r) * 3072 + hk + k8;
            else if (k8 < 128) s = qk_lo + lo_base + (size_t)(ch * 64 + r) * 2048 + lk + (k8 - 64);
            else               s = qkv_hi + hi_base + (size_t)(ch * 64 + r) * 3072 + hk + (k8 - 128);
            kreg[p] = *(const short8v*)s;
        }
        const unsigned short* vsrc = qkv_hi + hi_base + (size_t)(ch * 64 + kr) * 3072 + hv + d0;
        vreg[0] = *(const short8v*)vsrc;
        vreg[1] = *(const short8v*)(vsrc + 8);
    };

    auto load_mask = [&](int ch) {
#pragma unroll
        for (int n = 0; n < 4; ++n)
#pragma unroll
            for (int r = 0; r < 4; ++r)
                mreg[n * 4 + r] = maskT[(size_t)(ch * 64 + n * 16 + lg * 4 + r) * 1024
                                        + qb * 64 + w * 16 + i];
    };

    auto write_ch = [&]() {
#pragma unroll
        for (int p = 0; p < 6; ++p) {
            int c = p * 256 + tid;
            int r = c / 24, k8 = (c % 24) * 8;
            *(short8v*)&Ks[r * QP + k8] = kreg[p];
        }
        {
            unsigned kh = kr >> 3, klo = kr & 7;
#pragma unroll
            for (int j = 0; j < 16; ++j) {
                unsigned short vv = (j < 8) ? (unsigned short)vreg[0][j] : (unsigned short)vreg[1][j - 8];
                int d = d0 + j;
                VT[d * VP + ((kh ^ ((d >> 3) & 7)) * 8 + klo)] = vv;
            }
        }
    };

    load_kv(0);
    load_mask(0);
    float m_run = -3e30f, l_run = 0.f;
    floatx4 accv[4] = {};
    const unsigned qsw = ((w * 16 + i) >> 2) & 7;

    for (int ch = 0; ch < 16; ++ch) {
        __syncthreads();
        write_ch();
        __syncthreads();
        if (ch < 15) load_kv(ch + 1);

        floatx4 sc[4] = {};
        __builtin_amdgcn_s_setprio(1);
#pragma unroll
        for (int ks = 0; ks < 6; ++ks) {
#pragma unroll
            for (int n = 0; n < 4; ++n) {
                short8v kf = *(const short8v*)&Ks[(n * 16 + i) * QP + ks * 32 + lg * 8];
                sc[n] = __builtin_amdgcn_mfma_f32_16x16x32_bf16(kf, qf[ks], sc[n], 0, 0, 0);
            }
        }
        __builtin_amdgcn_s_setprio(0);

        float sv[4][4];
        float cmax = -3e30f;
#pragma unroll
        for (int n = 0; n < 4; ++n)
#pragma unroll
            for (int r = 0; r < 4; ++r) {
                float val = sc[n][r] + mreg[n * 4 + r];
                sv[n][r] = val;
                cmax = fmaxf(cmax, val);
            }
        cmax = fmaxf(cmax, __shfl_xor(cmax, 16));
        cmax = fmaxf(cmax, __shfl_xor(cmax, 32));

        if (!__all(cmax - m_run <= 8.f)) {
            float mnew = fmaxf(m_run, cmax);
            float fct = __expf(m_run - mnew);
            m_run = mnew;
            l_run *= fct;
            float fr[4];
#pragma unroll
            for (int r = 0; r < 4; ++r) fr[r] = __shfl(fct, lg * 4 + r);
#pragma unroll
            for (int n = 0; n < 4; ++n)
#pragma unroll
                for (int r = 0; r < 4; ++r) accv[n][r] *= fr[r];
        }

        float rsum = 0.f;
        float pv[4][4];
#pragma unroll
        for (int n = 0; n < 4; ++n)
#pragma unroll
            for (int r = 0; r < 4; ++r) {
                float pp = __expf(sv[n][r] - m_run);
                pv[n][r] = pp;
                rsum += pp;
            }
        rsum += __shfl_xor(rsum, 16);
        rsum += __shfl_xor(rsum, 32);
        l_run += rsum;

        if (ch < 15) load_mask(ch + 1);

#pragma unroll
        for (int n = 0; n < 4; ++n)
#pragma unroll
            for (int u = 0; u < 2; ++u) {
                unsigned kh = 2 * n + (lg >> 1);
                unsigned klo = 4 * (lg & 1) + 2 * u;
                unsigned col = (kh ^ qsw) * 8 + klo;
                unsigned pk = (unsigned)f2bf(pv[n][2 * u]) | ((unsigned)f2bf(pv[n][2 * u + 1]) << 16);
                *(unsigned*)&Ps[(w * 16 + i) * VP + col] = pk;
            }

        __builtin_amdgcn_s_setprio(1);
#pragma unroll
        for (int ks = 0; ks < 2; ++ks) {
            short8v pf = *(const short8v*)&Ps[(w * 16 + i) * VP + ((ks * 4 + lg) ^ qsw) * 8];
#pragma unroll
            for (int n = 0; n < 4; ++n) {
                int d = n * 16 + i;
                short8v vf = *(const short8v*)&VT[d * VP + (((ks * 4 + lg) ^ ((d >> 3) & 7)) * 8)];
                accv[n] = __builtin_amdgcn_mfma_f32_16x16x32_bf16(pf, vf, accv[n], 0, 0, 0);
            }
        }
        __builtin_amdgcn_s_setprio(0);
    }

    float linv = 1.f / l_run;
    float lr[4];
#pragma unroll
    for (int r = 0; r < 4; ++r) lr[r] = __shfl(linv, lg * 4 + r);
#pragma unroll
    for (int r = 0; r < 4; ++r) {
        int s_ = qb * 64 + w * 16 + lg * 4 + r;
        size_t row2 = (size_t)(b * 1024 + h * 64 + (s_ >> 4)) * 2048;
        int colh = (s_ & 15) * 64;
#pragma unroll
        for (int n = 0; n < 4; ++n) {
            int d = n * 16 + i;
            float val = accv[n][r] * lr[r];
            unsigned short hh2 = f2bf(val);
            V2p[row2 + colh + d] = hh2;
            V2p[row2 + 1024 + colh + d] = f2bf(val - bf2f(hh2));
        }
    }
}

extern "C" void kernel_launch(void* const* d_in, const int* in_sizes, int n_in,
                              void* d_out, int out_size, void* d_ws, size_t ws_size,
                              hipStream_t stream)
{
    const float* x    = (const float*)d_in[0];
    const float* mask = (const float*)d_in[1];
    const float* Wqkv = (const float*)d_in[2];
    const float* bqkv = (const float*)d_in[3];
    const float* Wo   = (const float*)d_in[4];
    const float* bo   = (const float*)d_in[5];
    float* out = (float*)d_out;

    // workspace layout, peak 124 MiB:
    //   [0,32M)     Xp [8192][2048]   -> later V2p (Xp dead after gemm1)
    //   [32,80M)    qkv_hi [8192][3072]
    //   [80,112M)   qk_lo [8192][2048]
    //   [112,124M)  Wp [3072][2048]   -> later Wop [1024][2048] (@112M) +
    //                                    maskT [1024][1024] f32 (@116M)
    char* w = (char*)d_ws;
    unsigned short* Xp     = (unsigned short*)w;
    unsigned short* V2p    = (unsigned short*)w;
    unsigned short* qkv_hi = (unsigned short*)(w + 33554432);
    unsigned short* qk_lo  = (unsigned short*)(w + 83886080);
    unsigned short* Wp     = (unsigned short*)(w + 117440512);
    unsigned short* Wop    = (unsigned short*)(w + 117440512);
    float*          maskT  = (float*)(w + 117440512 + 4194304);

    conv_split<<<8192, 256, 0, stream>>>(x, Xp);        // X -> [Xh|Xl]
    conv_split<<<3072, 256, 0, stream>>>(Wqkv, Wp);     // Wqkv -> [h|l]

    gemm1_qkv8<<<dim3(24, 32), 512, 0, stream>>>(Xp, Wp, bqkv, qkv_hi, qk_lo);

    conv_split<<<1024, 256, 0, stream>>>(Wo, Wop);      // after gemm1 (aliases Wp)
    transpose_mask<<<dim3(16, 16), 256, 0, stream>>>(mask, maskT);

    attn_mfma3<<<dim3(16, 16, 8), 256, 0, stream>>>(qkv_hi, qk_lo, maskT, V2p);

    gemm2_out8<<<dim3(8, 32), 512, 0, stream>>>(V2p, Wop, bo, out);
}